// Round 17
// baseline (2551.536 us; speedup 1.0000x reference)
//
#include <hip/hip_runtime.h>

#define LROWS 8
#define MCOLS 8
#define BD 32
#define NSITE 64
#define SPB 64
#define BTOT 32768
#define NBLK (BTOT / SPB)   // 512
#define EPS 1e-10
#define PI_D 3.14159265358979323846

// ws layout (doubles) — identical to round 13:
//  W : [site][role16][b32][a4][2] (mh,mv pairs) = 262144
//  CB: [site][role16][12] (v4 | eta2_4 | w4)    = 12288   @ 262144
//  CC: [site] c scalar                          = 64      @ 274432
#define W_OFF 0
#define CB_OFF 262144
#define CC_OFF (262144 + 12288)
#define WS_DBLS (CC_OFF + 64)

__global__ void precompute_kernel(const float* __restrict__ M_h,
                                  const float* __restrict__ M_v,
                                  const float* __restrict__ v,
                                  const float* __restrict__ w,
                                  const float* __restrict__ cc,
                                  const float* __restrict__ eta,
                                  double* __restrict__ ws) {
    int idx = blockIdx.x * 256 + threadIdx.x;
    if (idx >= WS_DBLS) return;
    double val = 0.0;
    if (idx < CB_OFF) {
        int pair = idx & 1, a4 = (idx >> 1) & 3, b = (idx >> 3) & 31;
        int r = (idx >> 8) & 15, site = idx >> 12;
        int i = site >> 3, js = site & 7;
        int c = (i & 1) ? (MCOLS - 1 - js) : js;
        int s = r >> 3, a = (r & 7) * 4 + a4;
        if (pair == 0) val = (double)M_h[(((i * MCOLS + c) * 2 + s) * BD + a) * BD + b];
        else           val = (double)M_v[(((i * MCOLS + c) * 2 + s) * BD + a) * BD + b];
    } else if (idx < CC_OFF) {
        int j = idx - CB_OFF;
        int site = j / 192;
        int rem = j - site * 192;
        int r = rem / 12, t = rem - r * 12;
        int i = site >> 3, js = site & 7;
        int c = (i & 1) ? (MCOLS - 1 - js) : js;
        int s = r >> 3, a0 = (r & 7) * 4;
        if (t < 4)      val = (double)v[(((i * MCOLS + c) * 2 + s) * BD) + a0 + t];
        else if (t < 8) { double e = (double)eta[(i * MCOLS + c) * BD + a0 + (t - 4)]; val = e * e; }
        else            val = (double)w[(i * MCOLS + c) * BD + a0 + (t - 8)];
    } else {
        int site = idx - CC_OFF;
        int i = site >> 3, js = site & 7;
        int c = (i & 1) ? (MCOLS - 1 - js) : js;
        val = (double)cc[i * MCOLS + c];
    }
    ws[idx] = val;
}

__launch_bounds__(1024, 1)
__global__ void mps_main_kernel(const int* __restrict__ x,
                                const double* __restrict__ ws,
                                float* __restrict__ out) {
    __shared__ double hRow[MCOLS][BD][SPB];   // 128 KB, lattice-column indexed
    __shared__ float  pbuf[2][16][SPB];       // 8 KB  (parity dbuf; feeds la only -> fp32 ok)
    __shared__ double ssb[8][SPB];            // 4 KB  (complementary-mask slot r&7, in-window)
    __shared__ double phb[2][8][SPB];         // 8 KB  (parity dbuf, complementary-mask slot)
    // total 148 KB -> 1 block/CU, 16 waves = 4/SIMD

    const int tid = threadIdx.x;
    const int k = tid & 63;                  // lane = sample slot
    const int r = tid >> 6;                  // role = s*8 + a-quartet, wave-uniform
    const int r_u = __builtin_amdgcn_readfirstlane(r);
    const int s = r_u >> 3;
    const int abase = (r_u & 7) * 4;
    const int j8 = r_u & 7;                  // complementary slot (s=0 and s=1 waves share)
    const long kg = (long)blockIdx.x * SPB + k;

    // asm-opaque per-lane zero: forces weight loads onto the VMEM path (vmcnt),
    // decoupling them from LDS's lgkmcnt (SMEM returns out-of-order -> lgkmcnt(0) drains).
    int vz;
    asm("v_mov_b32 %0, 0" : "=v"(vz));

    for (int t = tid; t < MCOLS * BD * SPB; t += 1024) (&hRow[0][0][0])[t] = 0.0;
    __syncthreads();

    const double2* __restrict__ Wp = (const double2*)ws;  // double2 = (mh, mv)

    double la = 0.0, ph = 0.0;
    double prodN = 1.0, prodD = 1.0;
    int par = 0;
    double2 wreg[2][8];   // double-buffered weight prefetch (2 b-iters deep), VGPR-resident

    {   // preload site 0, block 0 (VMEM)
        const double2* __restrict__ w0 =
            (const double2*)((const char*)(Wp + (size_t)r_u * 128) + vz);
        #pragma unroll
        for (int t = 0; t < 8; ++t) wreg[0][t] = w0[t];
    }

    for (int i = 0; i < LROWS; ++i) {
        const int* xp = x + kg * NSITE + i * MCOLS;
        int4 xa = *reinterpret_cast<const int4*>(xp);
        int4 xb = *reinterpret_cast<const int4*>(xp + 4);
        const unsigned xbits = (unsigned)((xa.x & 1)        | ((xa.y & 1) << 1) |
                                          ((xa.z & 1) << 2) | ((xa.w & 1) << 3) |
                                          ((xb.x & 1) << 4) | ((xb.y & 1) << 5) |
                                          ((xb.z & 1) << 6) | ((xb.w & 1) << 7));
        prodN = 1.0; prodD = 1.0;

        for (int js = 0; js < MCOLS; ++js) {
            const int site = i * MCOLS + js;
            const int c = (i & 1) ? (MCOLS - 1 - js) : js;
            const int cprev = (i & 1) ? (MCOLS - js) : (js - 1);

            const double2* __restrict__ wsite =
                (const double2*)((const char*)(Wp + (size_t)(site * 16 + r_u) * 128) + vz);
            const double*  __restrict__ cb =
                (const double*)((const char*)(ws + CB_OFF + (size_t)(site * 16 + r_u) * 12) + vz);

            const double* __restrict__ colV = &hRow[c][0][0];

            double acc[4];
            #pragma unroll
            for (int a = 0; a < 4; ++a) acc[a] = 0.0;

            // ---- software-pipelined matvec: 16 blocks of 2 b-iters (r13 verbatim) ----
            if (js == 0) {
                #pragma unroll
                for (int bb = 0; bb < 16; ++bb) {
                    const int cur = bb & 1;
                    if (bb < 15) {
                        const double2* __restrict__ wn = wsite + (bb + 1) * 8;
                        #pragma unroll
                        for (int t = 0; t < 8; ++t) wreg[cur ^ 1][t] = wn[t];
                    }
                    #pragma unroll
                    for (int bq = 0; bq < 2; ++bq) {
                        const int b = bb * 2 + bq;
                        const double hvb = colV[b * SPB + k];
                        #pragma unroll
                        for (int a = 0; a < 4; ++a) {
                            const double2 w2 = wreg[cur][bq * 4 + a];
                            acc[a] = fma(w2.y, hvb, acc[a] + w2.x);   // h_left = 1
                        }
                    }
                }
            } else {
                const double* __restrict__ colL = &hRow[cprev][0][0];
                #pragma unroll
                for (int bb = 0; bb < 16; ++bb) {
                    const int cur = bb & 1;
                    if (bb < 15) {
                        const double2* __restrict__ wn = wsite + (bb + 1) * 8;
                        #pragma unroll
                        for (int t = 0; t < 8; ++t) wreg[cur ^ 1][t] = wn[t];
                    }
                    #pragma unroll
                    for (int bq = 0; bq < 2; ++bq) {
                        const int b = bb * 2 + bq;
                        const double hlb = colL[b * SPB + k];
                        const double hvb = colV[b * SPB + k];
                        #pragma unroll
                        for (int a = 0; a < 4; ++a) {
                            const double2 w2 = wreg[cur][bq * 4 + a];
                            acc[a] = fma(w2.x, hlb, fma(w2.y, hvb, acc[a]));
                        }
                    }
                }
            }
            #pragma unroll
            for (int a = 0; a < 4; ++a) acc[a] += cb[a];   // v bias (late add)

            // partials over this role's 4 accs
            double pp = 0.0, ssp = 0.0, php = 0.0;
            #pragma unroll
            for (int a = 0; a < 4; ++a) {
                const double t2 = acc[a] * acc[a];
                pp  = fma(t2, cb[4 + a], pp);
                ssp += t2;
                php = fma(acc[a], cb[8 + a], php);
            }
            const double ccoef = *(const double*)((const char*)(ws + CC_OFF + site) + vz);
            const int xs = (int)((xbits >> js) & 1u);
            const bool sel = (s == xs);

            pbuf[par][r][k] = (float)pp;
            if (sel) { ssb[j8][k] = ssp; phb[par][j8][k] = php; }  // complementary lane masks
            __syncthreads();   // bar1: partials visible

            // prefetch NEXT site's block 0 (VMEM; overlaps window; site 63 -> in-bounds read)
            {
                const double2* __restrict__ wn =
                    (const double2*)((const char*)(Wp + (size_t)((site + 1) * 16 + r_u) * 128) + vz);
                #pragma unroll
                for (int t = 0; t < 8; ++t) wreg[0][t] = wn[t];
            }

            // ---- minimal window: ss reduce + inv + hRow write only ----
            const double ss = (((ssb[0][k] + ssb[1][k]) + (ssb[2][k] + ssb[3][k]))
                             + ((ssb[4][k] + ssb[5][k]) + (ssb[6][k] + ssb[7][k])));
            const double inv = 1.0 / (sqrt(ss) + EPS);
            if (sel) {
                #pragma unroll
                for (int a = 0; a < 4; ++a)
                    hRow[c][abase + a][k] = acc[a] * inv;   // h_left next site / h_below next row
            }
            __syncthreads();   // bar2: hRow updated

            // ---- epilogue (wave 0 only): overlaps other waves' next matvec ----
            if (r_u == 0) {
                const float* __restrict__ pb = &pbuf[par][0][0];
                const double p0 = (double)((((pb[0*SPB+k] + pb[1*SPB+k]) + (pb[2*SPB+k] + pb[3*SPB+k]))
                                          + ((pb[4*SPB+k] + pb[5*SPB+k]) + (pb[6*SPB+k] + pb[7*SPB+k]))));
                const double p1 = (double)((((pb[8*SPB+k] + pb[9*SPB+k]) + (pb[10*SPB+k] + pb[11*SPB+k]))
                                          + ((pb[12*SPB+k] + pb[13*SPB+k]) + (pb[14*SPB+k] + pb[15*SPB+k]))));
                const double psel = xs ? p1 : p0;
                prodN *= (psel + EPS);
                prodD *= (p0 + p1 + EPS);
                const double phd = (((phb[par][0][k] + phb[par][1][k]) + (phb[par][2][k] + phb[par][3][k]))
                                  + ((phb[par][4][k] + phb[par][5][k]) + (phb[par][6][k] + phb[par][7][k])));
                const double aph = phd * inv + ccoef;
                ph += (aph < 0.0) ? PI_D : 0.0;
            }
            par ^= 1;
        }
        if (r_u == 0) la += 0.5 * (log(prodN) - log(prodD));
    }

    if (r == 0) {
        out[kg * 2]     = (float)la;
        out[kg * 2 + 1] = (float)ph;
    }
}

extern "C" void kernel_launch(void* const* d_in, const int* in_sizes, int n_in,
                              void* d_out, int out_size, void* d_ws, size_t ws_size,
                              hipStream_t stream) {
    const int*   x    = (const int*)d_in[0];
    const float* M_h  = (const float*)d_in[1];
    const float* M_v  = (const float*)d_in[2];
    const float* v    = (const float*)d_in[3];
    const float* w    = (const float*)d_in[4];
    const float* cc   = (const float*)d_in[5];
    const float* eta  = (const float*)d_in[6];
    float* out = (float*)d_out;
    double* ws = (double*)d_ws;

    const int pre_total = WS_DBLS;
    dim3 preGrid((pre_total + 255) / 256), preBlock(256);
    hipLaunchKernelGGL(precompute_kernel, preGrid, preBlock, 0, stream,
                       M_h, M_v, v, w, cc, eta, ws);

    dim3 grid(NBLK), block(1024);
    hipLaunchKernelGGL(mps_main_kernel, grid, block, 0, stream, x, ws, out);
}

// Round 18
// 701.708 us; speedup vs baseline: 3.6362x; 3.6362x over previous
//
#include <hip/hip_runtime.h>

#define LROWS 8
#define MCOLS 8
#define BD 32
#define NSITE 64
#define SPB 64
#define BTOT 32768
#define NBLK (BTOT / SPB)   // 512
#define EPS 1e-10
#define PI_D 3.14159265358979323846

// ws layout (doubles) — identical to round 13:
//  W : [site][role16][b32][a4][2] (mh,mv pairs) = 262144
//  CB: [site][role16][12] (v4 | eta2_4 | w4)    = 12288   @ 262144
//  CC: [site] c scalar                          = 64      @ 274432
#define W_OFF 0
#define CB_OFF 262144
#define CC_OFF (262144 + 12288)
#define WS_DBLS (CC_OFF + 64)

__global__ void precompute_kernel(const float* __restrict__ M_h,
                                  const float* __restrict__ M_v,
                                  const float* __restrict__ v,
                                  const float* __restrict__ w,
                                  const float* __restrict__ cc,
                                  const float* __restrict__ eta,
                                  double* __restrict__ ws) {
    int idx = blockIdx.x * 256 + threadIdx.x;
    if (idx >= WS_DBLS) return;
    double val = 0.0;
    if (idx < CB_OFF) {
        int pair = idx & 1, a4 = (idx >> 1) & 3, b = (idx >> 3) & 31;
        int r = (idx >> 8) & 15, site = idx >> 12;
        int i = site >> 3, js = site & 7;
        int c = (i & 1) ? (MCOLS - 1 - js) : js;
        int s = r >> 3, a = (r & 7) * 4 + a4;
        if (pair == 0) val = (double)M_h[(((i * MCOLS + c) * 2 + s) * BD + a) * BD + b];
        else           val = (double)M_v[(((i * MCOLS + c) * 2 + s) * BD + a) * BD + b];
    } else if (idx < CC_OFF) {
        int j = idx - CB_OFF;
        int site = j / 192;
        int rem = j - site * 192;
        int r = rem / 12, t = rem - r * 12;
        int i = site >> 3, js = site & 7;
        int c = (i & 1) ? (MCOLS - 1 - js) : js;
        int s = r >> 3, a0 = (r & 7) * 4;
        if (t < 4)      val = (double)v[(((i * MCOLS + c) * 2 + s) * BD) + a0 + t];
        else if (t < 8) { double e = (double)eta[(i * MCOLS + c) * BD + a0 + (t - 4)]; val = e * e; }
        else            val = (double)w[(i * MCOLS + c) * BD + a0 + (t - 8)];
    } else {
        int site = idx - CC_OFF;
        int i = site >> 3, js = site & 7;
        int c = (i & 1) ? (MCOLS - 1 - js) : js;
        val = (double)cc[i * MCOLS + c];
    }
    ws[idx] = val;
}

__launch_bounds__(1024, 1)
__global__ void mps_main_kernel(const int* __restrict__ x,
                                const double* __restrict__ ws,
                                float* __restrict__ out) {
    __shared__ double2 hRow[MCOLS][BD / 2][SPB];  // 128 KB, b-paired: [col][b/2][k] = (h[2b'],h[2b'+1])
    __shared__ float  pbuf[2][16][SPB];           // 8 KB  (parity dbuf; feeds la only -> fp32 ok)
    __shared__ double ssb[8][SPB];                // 4 KB  (complementary-mask slot r&7, in-window)
    __shared__ double phb[2][8][SPB];             // 8 KB  (parity dbuf, complementary-mask slot)
    // total 148 KB -> 1 block/CU, 16 waves = 4/SIMD

    const int tid = threadIdx.x;
    const int k = tid & 63;                  // lane = sample slot
    const int r = tid >> 6;                  // role = s*8 + a-quartet, wave-uniform
    const int r_u = __builtin_amdgcn_readfirstlane(r);
    const int s = r_u >> 3;
    const int pb2 = (r_u & 7) * 2;           // pair-row base for this role's 4 accs
    const int j8 = r_u & 7;                  // complementary slot (s=0 and s=1 waves share)
    const long kg = (long)blockIdx.x * SPB + k;

    for (int t = tid; t < MCOLS * (BD / 2) * SPB; t += 1024) {
        double2 z; z.x = 0.0; z.y = 0.0;
        (&hRow[0][0][0])[t] = z;
    }
    __syncthreads();

    const double2* __restrict__ Wp = (const double2*)ws;  // double2 = (mh, mv)

    double la = 0.0, ph = 0.0;
    double prodN = 1.0, prodD = 1.0;
    int par = 0;
    double2 wreg[2][8];   // double-buffered uniform weight prefetch (2 b-iters deep)

    {   // preload site 0, block 0
        const double2* __restrict__ w0 = Wp + (size_t)r_u * 128;
        #pragma unroll
        for (int t = 0; t < 8; ++t) wreg[0][t] = w0[t];
    }

    for (int i = 0; i < LROWS; ++i) {
        const int* xp = x + kg * NSITE + i * MCOLS;
        int4 xa = *reinterpret_cast<const int4*>(xp);
        int4 xb = *reinterpret_cast<const int4*>(xp + 4);
        const unsigned xbits = (unsigned)((xa.x & 1)        | ((xa.y & 1) << 1) |
                                          ((xa.z & 1) << 2) | ((xa.w & 1) << 3) |
                                          ((xb.x & 1) << 4) | ((xb.y & 1) << 5) |
                                          ((xb.z & 1) << 6) | ((xb.w & 1) << 7));
        prodN = 1.0; prodD = 1.0;

        for (int js = 0; js < MCOLS; ++js) {
            const int site = i * MCOLS + js;
            const int c = (i & 1) ? (MCOLS - 1 - js) : js;
            const int cprev = (i & 1) ? (MCOLS - js) : (js - 1);

            const double2* __restrict__ wsite = Wp + (size_t)(site * 16 + r_u) * 128;
            const double*  __restrict__ cb    = ws + CB_OFF + (size_t)(site * 16 + r_u) * 12;

            const double2* __restrict__ colV = &hRow[c][0][0];

            double acc[4];
            #pragma unroll
            for (int a = 0; a < 4; ++a) acc[a] = 0.0;

            // ---- software-pipelined matvec: 16 blocks of 2 b-iters; h via paired b128 ----
            if (js == 0) {
                #pragma unroll
                for (int bb = 0; bb < 16; ++bb) {
                    const int cur = bb & 1;
                    if (bb < 15) {
                        const double2* __restrict__ wn = wsite + (bb + 1) * 8;
                        #pragma unroll
                        for (int t = 0; t < 8; ++t) wreg[cur ^ 1][t] = wn[t];
                    }
                    const double2 hv2 = colV[bb * SPB + k];   // h[2bb], h[2bb+1]
                    #pragma unroll
                    for (int bq = 0; bq < 2; ++bq) {
                        const double hvb = (bq == 0) ? hv2.x : hv2.y;
                        #pragma unroll
                        for (int a = 0; a < 4; ++a) {
                            const double2 w2 = wreg[cur][bq * 4 + a];
                            acc[a] = fma(w2.y, hvb, acc[a] + w2.x);   // h_left = 1
                        }
                    }
                }
            } else {
                const double2* __restrict__ colL = &hRow[cprev][0][0];
                #pragma unroll
                for (int bb = 0; bb < 16; ++bb) {
                    const int cur = bb & 1;
                    if (bb < 15) {
                        const double2* __restrict__ wn = wsite + (bb + 1) * 8;
                        #pragma unroll
                        for (int t = 0; t < 8; ++t) wreg[cur ^ 1][t] = wn[t];
                    }
                    const double2 hl2 = colL[bb * SPB + k];
                    const double2 hv2 = colV[bb * SPB + k];
                    #pragma unroll
                    for (int bq = 0; bq < 2; ++bq) {
                        const double hlb = (bq == 0) ? hl2.x : hl2.y;
                        const double hvb = (bq == 0) ? hv2.x : hv2.y;
                        #pragma unroll
                        for (int a = 0; a < 4; ++a) {
                            const double2 w2 = wreg[cur][bq * 4 + a];
                            acc[a] = fma(w2.x, hlb, fma(w2.y, hvb, acc[a]));
                        }
                    }
                }
            }
            #pragma unroll
            for (int a = 0; a < 4; ++a) acc[a] += cb[a];   // v bias (late add)

            // partials over this role's 4 accs
            double pp = 0.0, ssp = 0.0, php = 0.0;
            #pragma unroll
            for (int a = 0; a < 4; ++a) {
                const double t2 = acc[a] * acc[a];
                pp  = fma(t2, cb[4 + a], pp);
                ssp += t2;
                php = fma(acc[a], cb[8 + a], php);
            }
            const double ccoef = ws[CC_OFF + site];
            const int xs = (int)((xbits >> js) & 1u);
            const bool sel = (s == xs);

            pbuf[par][r][k] = (float)pp;
            if (sel) { ssb[j8][k] = ssp; phb[par][j8][k] = php; }  // complementary lane masks
            __syncthreads();   // bar1: partials visible

            // prefetch NEXT site's block 0 (overlaps window; site 63 -> harmless in-bounds read)
            {
                const double2* __restrict__ wn = Wp + (size_t)((site + 1) * 16 + r_u) * 128;
                #pragma unroll
                for (int t = 0; t < 8; ++t) wreg[0][t] = wn[t];
            }

            // ---- minimal window: ss reduce + inv + paired hRow write only ----
            const double ss = (((ssb[0][k] + ssb[1][k]) + (ssb[2][k] + ssb[3][k]))
                             + ((ssb[4][k] + ssb[5][k]) + (ssb[6][k] + ssb[7][k])));
            const double inv = 1.0 / (sqrt(ss) + EPS);
            if (sel) {
                double2 h0; h0.x = acc[0] * inv; h0.y = acc[1] * inv;
                double2 h1; h1.x = acc[2] * inv; h1.y = acc[3] * inv;
                hRow[c][pb2][k]     = h0;   // b128 write: rows 2*pb2, 2*pb2+1
                hRow[c][pb2 + 1][k] = h1;
            }
            __syncthreads();   // bar2: hRow updated

            // ---- epilogue (wave 0 only): overlaps other waves' next matvec ----
            if (r_u == 0) {
                const float* __restrict__ pb = &pbuf[par][0][0];
                const double p0 = (double)((((pb[0*SPB+k] + pb[1*SPB+k]) + (pb[2*SPB+k] + pb[3*SPB+k]))
                                          + ((pb[4*SPB+k] + pb[5*SPB+k]) + (pb[6*SPB+k] + pb[7*SPB+k]))));
                const double p1 = (double)((((pb[8*SPB+k] + pb[9*SPB+k]) + (pb[10*SPB+k] + pb[11*SPB+k]))
                                          + ((pb[12*SPB+k] + pb[13*SPB+k]) + (pb[14*SPB+k] + pb[15*SPB+k]))));
                const double psel = xs ? p1 : p0;
                prodN *= (psel + EPS);
                prodD *= (p0 + p1 + EPS);
                const double phd = (((phb[par][0][k] + phb[par][1][k]) + (phb[par][2][k] + phb[par][3][k]))
                                  + ((phb[par][4][k] + phb[par][5][k]) + (phb[par][6][k] + phb[par][7][k])));
                const double aph = phd * inv + ccoef;
                ph += (aph < 0.0) ? PI_D : 0.0;
            }
            par ^= 1;
        }
        if (r_u == 0) la += 0.5 * (log(prodN) - log(prodD));
    }

    if (r == 0) {
        out[kg * 2]     = (float)la;
        out[kg * 2 + 1] = (float)ph;
    }
}

extern "C" void kernel_launch(void* const* d_in, const int* in_sizes, int n_in,
                              void* d_out, int out_size, void* d_ws, size_t ws_size,
                              hipStream_t stream) {
    const int*   x    = (const int*)d_in[0];
    const float* M_h  = (const float*)d_in[1];
    const float* M_v  = (const float*)d_in[2];
    const float* v    = (const float*)d_in[3];
    const float* w    = (const float*)d_in[4];
    const float* cc   = (const float*)d_in[5];
    const float* eta  = (const float*)d_in[6];
    float* out = (float*)d_out;
    double* ws = (double*)d_ws;

    const int pre_total = WS_DBLS;
    dim3 preGrid((pre_total + 255) / 256), preBlock(256);
    hipLaunchKernelGGL(precompute_kernel, preGrid, preBlock, 0, stream,
                       M_h, M_v, v, w, cc, eta, ws);

    dim3 grid(NBLK), block(1024);
    hipLaunchKernelGGL(mps_main_kernel, grid, block, 0, stream, x, ws, out);
}

// Round 19
// 654.143 us; speedup vs baseline: 3.9006x; 1.0727x over previous
//
#include <hip/hip_runtime.h>

#define LROWS 8
#define MCOLS 8
#define BD 32
#define NSITE 64
#define SPB 64
#define BTOT 32768
#define NBLK (BTOT / SPB)   // 512
#define EPS 1e-10
#define PI_D 3.14159265358979323846

// ws layout (doubles) — round 13 champion:
//  W : [site][role16][b32][a4][2] (mh,mv pairs) = 262144
//  CB: [site][role16][12] (v4 | eta2_4 | w4)    = 12288   @ 262144
//  CC: [site] c scalar                          = 64      @ 274432
#define W_OFF 0
#define CB_OFF 262144
#define CC_OFF (262144 + 12288)
#define WS_DBLS (CC_OFF + 64)

__global__ void precompute_kernel(const float* __restrict__ M_h,
                                  const float* __restrict__ M_v,
                                  const float* __restrict__ v,
                                  const float* __restrict__ w,
                                  const float* __restrict__ cc,
                                  const float* __restrict__ eta,
                                  double* __restrict__ ws) {
    int idx = blockIdx.x * 256 + threadIdx.x;
    if (idx >= WS_DBLS) return;
    double val = 0.0;
    if (idx < CB_OFF) {
        int pair = idx & 1, a4 = (idx >> 1) & 3, b = (idx >> 3) & 31;
        int r = (idx >> 8) & 15, site = idx >> 12;
        int i = site >> 3, js = site & 7;
        int c = (i & 1) ? (MCOLS - 1 - js) : js;
        int s = r >> 3, a = (r & 7) * 4 + a4;
        if (pair == 0) val = (double)M_h[(((i * MCOLS + c) * 2 + s) * BD + a) * BD + b];
        else           val = (double)M_v[(((i * MCOLS + c) * 2 + s) * BD + a) * BD + b];
    } else if (idx < CC_OFF) {
        int j = idx - CB_OFF;
        int site = j / 192;
        int rem = j - site * 192;
        int r = rem / 12, t = rem - r * 12;
        int i = site >> 3, js = site & 7;
        int c = (i & 1) ? (MCOLS - 1 - js) : js;
        int s = r >> 3, a0 = (r & 7) * 4;
        if (t < 4)      val = (double)v[(((i * MCOLS + c) * 2 + s) * BD) + a0 + t];
        else if (t < 8) { double e = (double)eta[(i * MCOLS + c) * BD + a0 + (t - 4)]; val = e * e; }
        else            val = (double)w[(i * MCOLS + c) * BD + a0 + (t - 8)];
    } else {
        int site = idx - CC_OFF;
        int i = site >> 3, js = site & 7;
        int c = (i & 1) ? (MCOLS - 1 - js) : js;
        val = (double)cc[i * MCOLS + c];
    }
    ws[idx] = val;
}

__launch_bounds__(1024, 1)
__global__ void mps_main_kernel(const int* __restrict__ x,
                                const double* __restrict__ ws,
                                float* __restrict__ out) {
    __shared__ double hRow[MCOLS][BD][SPB];   // 128 KB, lattice-column indexed
    __shared__ float  pbuf[2][16][SPB];       // 8 KB  (parity dbuf; feeds la only -> fp32 ok)
    __shared__ double ssb[16 >> 1][SPB];      // 4 KB  (complementary-mask slot r&7, in-window)
    __shared__ double phb[2][8][SPB];         // 8 KB  (parity dbuf, complementary-mask slot r&7)
    // total 148 KB -> 1 block/CU, 16 waves = 4/SIMD

    const int tid = threadIdx.x;
    const int k = tid & 63;                  // lane = sample slot
    const int r = tid >> 6;                  // role = s*8 + a-quartet, wave-uniform
    const int r_u = __builtin_amdgcn_readfirstlane(r);
    const int s = r_u >> 3;
    const int abase = (r_u & 7) * 4;
    const int j8 = r_u & 7;                  // complementary slot (s=0 and s=1 waves share)
    const long kg = (long)blockIdx.x * SPB + k;

    for (int t = tid; t < MCOLS * BD * SPB; t += 1024) (&hRow[0][0][0])[t] = 0.0;
    __syncthreads();

    const double2* __restrict__ Wp = (const double2*)ws;  // double2 = (mh, mv)

    double la = 0.0, ph = 0.0;
    double prodN = 1.0, prodD = 1.0;
    int par = 0;
    double2 wreg[2][8];   // double-buffered uniform weight prefetch (2 b-iters deep)

    {   // preload site 0, block 0
        const double2* __restrict__ w0 = Wp + (size_t)r_u * 128;
        #pragma unroll
        for (int t = 0; t < 8; ++t) wreg[0][t] = w0[t];
    }

    for (int i = 0; i < LROWS; ++i) {
        const int* xp = x + kg * NSITE + i * MCOLS;
        int4 xa = *reinterpret_cast<const int4*>(xp);
        int4 xb = *reinterpret_cast<const int4*>(xp + 4);
        const unsigned xbits = (unsigned)((xa.x & 1)        | ((xa.y & 1) << 1) |
                                          ((xa.z & 1) << 2) | ((xa.w & 1) << 3) |
                                          ((xb.x & 1) << 4) | ((xb.y & 1) << 5) |
                                          ((xb.z & 1) << 6) | ((xb.w & 1) << 7));
        prodN = 1.0; prodD = 1.0;

        for (int js = 0; js < MCOLS; ++js) {
            const int site = i * MCOLS + js;
            const int c = (i & 1) ? (MCOLS - 1 - js) : js;
            const int cprev = (i & 1) ? (MCOLS - js) : (js - 1);

            const double2* __restrict__ wsite = Wp + (size_t)(site * 16 + r_u) * 128;
            const double*  __restrict__ cb    = ws + CB_OFF + (size_t)(site * 16 + r_u) * 12;

            const double* __restrict__ colV = &hRow[c][0][0];

            double acc[4];
            #pragma unroll
            for (int a = 0; a < 4; ++a) acc[a] = 0.0;

            // ---- software-pipelined matvec: 16 blocks of 2 b-iters ----
            if (js == 0) {
                #pragma unroll
                for (int bb = 0; bb < 16; ++bb) {
                    const int cur = bb & 1;
                    if (bb < 15) {
                        const double2* __restrict__ wn = wsite + (bb + 1) * 8;
                        #pragma unroll
                        for (int t = 0; t < 8; ++t) wreg[cur ^ 1][t] = wn[t];
                    }
                    #pragma unroll
                    for (int bq = 0; bq < 2; ++bq) {
                        const int b = bb * 2 + bq;
                        const double hvb = colV[b * SPB + k];
                        #pragma unroll
                        for (int a = 0; a < 4; ++a) {
                            const double2 w2 = wreg[cur][bq * 4 + a];
                            acc[a] = fma(w2.y, hvb, acc[a] + w2.x);   // h_left = 1
                        }
                    }
                }
            } else {
                const double* __restrict__ colL = &hRow[cprev][0][0];
                #pragma unroll
                for (int bb = 0; bb < 16; ++bb) {
                    const int cur = bb & 1;
                    if (bb < 15) {
                        const double2* __restrict__ wn = wsite + (bb + 1) * 8;
                        #pragma unroll
                        for (int t = 0; t < 8; ++t) wreg[cur ^ 1][t] = wn[t];
                    }
                    #pragma unroll
                    for (int bq = 0; bq < 2; ++bq) {
                        const int b = bb * 2 + bq;
                        const double hlb = colL[b * SPB + k];
                        const double hvb = colV[b * SPB + k];
                        #pragma unroll
                        for (int a = 0; a < 4; ++a) {
                            const double2 w2 = wreg[cur][bq * 4 + a];
                            acc[a] = fma(w2.x, hlb, fma(w2.y, hvb, acc[a]));
                        }
                    }
                }
            }
            #pragma unroll
            for (int a = 0; a < 4; ++a) acc[a] += cb[a];   // v bias (late add)

            // partials over this role's 4 accs
            double pp = 0.0, ssp = 0.0, php = 0.0;
            #pragma unroll
            for (int a = 0; a < 4; ++a) {
                const double t2 = acc[a] * acc[a];
                pp  = fma(t2, cb[4 + a], pp);
                ssp += t2;
                php = fma(acc[a], cb[8 + a], php);
            }
            const double ccoef = ws[CC_OFF + site];
            const int xs = (int)((xbits >> js) & 1u);
            const bool sel = (s == xs);

            pbuf[par][r][k] = (float)pp;
            if (sel) { ssb[j8][k] = ssp; phb[par][j8][k] = php; }  // complementary lane masks
            __syncthreads();   // bar1: partials visible

            // prefetch NEXT site's block 0 (drained by bar2 = covered by window)
            {
                const double2* __restrict__ wn = Wp + (size_t)((site + 1) * 16 + r_u) * 128;
                #pragma unroll
                for (int t = 0; t < 8; ++t) wreg[0][t] = wn[t];
            }

            // ---- minimal window: ss reduce + inv + hRow write only ----
            const double ss = (((ssb[0][k] + ssb[1][k]) + (ssb[2][k] + ssb[3][k]))
                             + ((ssb[4][k] + ssb[5][k]) + (ssb[6][k] + ssb[7][k])));
            const double inv = 1.0 / (sqrt(ss) + EPS);
            if (sel) {
                #pragma unroll
                for (int a = 0; a < 4; ++a)
                    hRow[c][abase + a][k] = acc[a] * inv;   // h_left next site / h_below next row
            }
            __syncthreads();   // bar2: hRow updated

            // ---- epilogue (wave 0 only): overlaps other waves' next matvec ----
            if (r_u == 0) {
                const float* __restrict__ pb = &pbuf[par][0][0];
                const double p0 = (double)((((pb[0*SPB+k] + pb[1*SPB+k]) + (pb[2*SPB+k] + pb[3*SPB+k]))
                                          + ((pb[4*SPB+k] + pb[5*SPB+k]) + (pb[6*SPB+k] + pb[7*SPB+k]))));
                const double p1 = (double)((((pb[8*SPB+k] + pb[9*SPB+k]) + (pb[10*SPB+k] + pb[11*SPB+k]))
                                          + ((pb[12*SPB+k] + pb[13*SPB+k]) + (pb[14*SPB+k] + pb[15*SPB+k]))));
                const double psel = xs ? p1 : p0;
                prodN *= (psel + EPS);
                prodD *= (p0 + p1 + EPS);
                const double phd = (((phb[par][0][k] + phb[par][1][k]) + (phb[par][2][k] + phb[par][3][k]))
                                  + ((phb[par][4][k] + phb[par][5][k]) + (phb[par][6][k] + phb[par][7][k])));
                const double aph = phd * inv + ccoef;
                ph += (aph < 0.0) ? PI_D : 0.0;
            }
            par ^= 1;
        }
        if (r_u == 0) la += 0.5 * (log(prodN) - log(prodD));
    }

    if (r == 0) {
        out[kg * 2]     = (float)la;
        out[kg * 2 + 1] = (float)ph;
    }
}

extern "C" void kernel_launch(void* const* d_in, const int* in_sizes, int n_in,
                              void* d_out, int out_size, void* d_ws, size_t ws_size,
                              hipStream_t stream) {
    const int*   x    = (const int*)d_in[0];
    const float* M_h  = (const float*)d_in[1];
    const float* M_v  = (const float*)d_in[2];
    const float* v    = (const float*)d_in[3];
    const float* w    = (const float*)d_in[4];
    const float* cc   = (const float*)d_in[5];
    const float* eta  = (const float*)d_in[6];
    float* out = (float*)d_out;
    double* ws = (double*)d_ws;

    const int pre_total = WS_DBLS;
    dim3 preGrid((pre_total + 255) / 256), preBlock(256);
    hipLaunchKernelGGL(precompute_kernel, preGrid, preBlock, 0, stream,
                       M_h, M_v, v, w, cc, eta, ws);

    dim3 grid(NBLK), block(1024);
    hipLaunchKernelGGL(mps_main_kernel, grid, block, 0, stream, x, ws, out);
}